// Round 7
// baseline (110.727 us; speedup 1.0000x reference)
//
#include <hip/hip_runtime.h>

#define P_TOT 30000
#define NPT   100
#define COUT  64

typedef __attribute__((ext_vector_type(2))) float f32x2;

static constexpr float VXf   = 0.16f;
static constexpr float VYf   = 0.16f;
static constexpr float XOFFf = 0.08f;            // VX/2 + 0.0
static constexpr float YOFFf = 0.08f - 39.68f;   // VY/2 + y_min
static constexpr float INV_M = 1.0f / 3000000.0f; // 1/(P*N)
static constexpr float NEGI  = -3.0e38f;

__device__ inline float wred(float v) {
#pragma unroll
  for (int d = 1; d < 64; d <<= 1) v += __shfl_xor(v, d);
  return v;
}

// K1: one pass over features. Per pillar (1 wave, lane = channel):
// points staged PAIR-TRANSPOSED in LDS: pair m -> slot 2m = {x0,x1,y0,y1},
// slot 2m+1 = {z0,z1,w0,w1}. Inner loop is packed-f32 (v_pk_fma/v_pk_max):
//   z2 = qx2*ce0 + qy2*ce1 + qz2*ce2 + qw2*ce3   (2 points/instr)
// Bias folded in closed form afterwards (r4-verified math):
//   ymax = zmax + b ; Sum(y) = Sz + np*b ; Sum(y^2) = Sq + b*(2*Sz + np*b)
__global__ __launch_bounds__(256) void k1_pk(
    const float4* __restrict__ feat, const int* __restrict__ npts,
    const int* __restrict__ coords, const float* __restrict__ W,
    float* __restrict__ ymax, float* __restrict__ partials, int nb) {
  const int lane = threadIdx.x & 63;
  const int wv   = threadIdx.x >> 6;
  const int wave_id = blockIdx.x * 4 + wv;
  const int nwaves  = nb * 4;

  // per-channel weights, affine-folded: ce = (w0+w4+w7, w1+w5+w8, w2+w6, w3)
  float wr[9];
#pragma unroll
  for (int i = 0; i < 9; i++) wr[i] = W[lane * 9 + i];
  const float ce0 = wr[0] + wr[4] + wr[7];
  const float ce1 = wr[1] + wr[5] + wr[8];
  const float ce2 = wr[2] + wr[6];
  const float ce3 = wr[3];
  const f32x2 cex2 = {ce0, ce0};
  const f32x2 cey2 = {ce1, ce1};
  const f32x2 cez2 = {ce2, ce2};
  const f32x2 cew2 = {ce3, ce3};

  float sum = 0.f, sumsq = 0.f;
  __shared__ float4 pts[4][NPT];   // pair-transposed staging, per wave

  const bool even = (lane & 1) == 0;

  for (int p = wave_id; p < P_TOT; p += nwaves) {
    const int np = npts[p];
    const float4* fp = feat + (size_t)p * NPT;
    float4 a0 = fp[lane];
    float4 a1 = make_float4(0.f, 0.f, 0.f, 0.f);
    if (lane < 36) a1 = fp[lane + 64];

    // reference: points_mean sums ALL 100 rows, divides by np
    const float sax = wred(a0.x + a1.x);
    const float say = wred(a0.y + a1.y);
    const float saz = wred(a0.z + a1.z);

    // pair-transpose exchange: even lane sends (z,w), odd sends (x,y)
    {
      const float s0 = even ? a0.z : a0.x;
      const float s1 = even ? a0.w : a0.y;
      const float r0 = __shfl_xor(s0, 1);
      const float r1 = __shfl_xor(s1, 1);
      // even lane -> slot 2m   = {x0, x1, y0, y1}
      // odd  lane -> slot 2m+1 = {z0, z1, w0, w1}
      pts[wv][lane] = even ? make_float4(a0.x, r0, a0.y, r1)
                           : make_float4(r0, a0.z, r1, a0.w);
    }
    if (lane < 36) {
      const float s0 = even ? a1.z : a1.x;
      const float s1 = even ? a1.w : a1.y;
      const float r0 = __shfl_xor(s0, 1);
      const float r1 = __shfl_xor(s1, 1);
      pts[wv][lane + 64] = even ? make_float4(a1.x, r0, a1.y, r1)
                                : make_float4(r0, a1.z, r1, a1.w);
    }
    asm volatile("s_waitcnt lgkmcnt(0)" ::: "memory");

    const float inv = 1.f / (float)np;
    const float cxc = (float)coords[p * 4 + 3] * VXf + XOFFf;
    const float cyc = (float)coords[p * 4 + 2] * VYf + YOFFf;
    float b = wr[4] * (sax * inv);
    b = fmaf(wr[5], say * inv, b);
    b = fmaf(wr[6], saz * inv, b);
    b = fmaf(wr[7], cxc, b);
    b = fmaf(wr[8], cyc, b);
    b = -b;

    const float4* base = pts[wv];
    f32x2 zmA = {NEGI, NEGI}, zmB = {NEGI, NEGI};
    f32x2 zsA = {0.f, 0.f}, zsB = {0.f, 0.f};
    f32x2 zqA = {0.f, 0.f}, zqB = {0.f, 0.f};

    const int Pp = np >> 1;   // full pairs
    int m = 0;
    for (; m + 2 <= Pp; m += 2) {
      const float4 u0 = base[2 * m];
      const float4 u1 = base[2 * m + 1];
      const float4 v0 = base[2 * m + 2];
      const float4 v1 = base[2 * m + 3];
      f32x2 z1 = f32x2{u0.x, u0.y} * cex2;
      f32x2 z2 = f32x2{v0.x, v0.y} * cex2;
      z1 += f32x2{u0.z, u0.w} * cey2;
      z2 += f32x2{v0.z, v0.w} * cey2;
      z1 += f32x2{u1.x, u1.y} * cez2;
      z2 += f32x2{v1.x, v1.y} * cez2;
      z1 += f32x2{u1.z, u1.w} * cew2;
      z2 += f32x2{v1.z, v1.w} * cew2;
      zmA = __builtin_elementwise_max(zmA, z1);
      zmB = __builtin_elementwise_max(zmB, z2);
      zsA += z1;
      zsB += z2;
      zqA += z1 * z1;
      zqB += z2 * z2;
    }
    if (m < Pp) {
      const float4 u0 = base[2 * m];
      const float4 u1 = base[2 * m + 1];
      f32x2 z1 = f32x2{u0.x, u0.y} * cex2;
      z1 += f32x2{u0.z, u0.w} * cey2;
      z1 += f32x2{u1.x, u1.y} * cez2;
      z1 += f32x2{u1.z, u1.w} * cew2;
      zmA = __builtin_elementwise_max(zmA, z1);
      zsA += z1;
      zqA += z1 * z1;
    }
    if (np & 1) {
      // last point np-1 (even parity) sits in pair Pp, parity-0 fields
      const float4 u0 = base[2 * Pp];
      const float4 u1 = base[2 * Pp + 1];
      float zx = u0.x * ce0;
      zx = fmaf(u0.z, ce1, zx);
      zx = fmaf(u1.x, ce2, zx);
      zx = fmaf(u1.z, ce3, zx);
      zmA.x = fmaxf(zmA.x, zx);
      zsA.x += zx;
      zqA.x = fmaf(zx, zx, zqA.x);
    }

    const float zm = fmaxf(fmaxf(zmA.x, zmA.y), fmaxf(zmB.x, zmB.y));
    const float zs = (zsA.x + zsA.y) + (zsB.x + zsB.y);
    const float zq = (zqA.x + zqA.y) + (zqB.x + zqB.y);
    const float npf = (float)np;
    ymax[p * COUT + lane] = zm + b;
    sum   += zs + npf * b;
    sumsq += zq + b * fmaf(npf, b, 2.f * zs);
  }

  __syncthreads();
  __shared__ float rs[4][64], rq[4][64];
  rs[wv][lane] = sum;
  rq[wv][lane] = sumsq;
  __syncthreads();
  const int t = threadIdx.x;
  if (t < 128) {
    const int c = t & 63;
    float v;
    if (t < 64) v = rs[0][c] + rs[1][c] + rs[2][c] + rs[3][c];
    else        v = rq[0][c] + rq[1][c] + rq[2][c] + rq[3][c];
    partials[blockIdx.x * 128 + t] = v;   // coalesced, block-major
  }
}

// K2: single block, 1024 threads, fully coalesced reduction of [nb][128]
__global__ __launch_bounds__(1024) void k2_reduce(
    const float* __restrict__ partials, int nb, float* __restrict__ S) {
  __shared__ float acc[8][128];
  const int m  = threadIdx.x & 127;
  const int bo = threadIdx.x >> 7;   // 0..7
  float s = 0.f;
  for (int b = bo; b < nb; b += 8) s += partials[b * 128 + m];
  acc[bo][m] = s;
  __syncthreads();
  if (threadIdx.x < 128) {
    float v = 0.f;
#pragma unroll
    for (int i = 0; i < 8; i++) v += acc[i][threadIdx.x];
    S[threadIdx.x] = v;
  }
}

// K3: finish in place on d_out. Each thread derives its channel's scale/shift
// from S (gamma==1 => scale>0, so max commutes with the BN affine).
__global__ __launch_bounds__(256) void k3_finish(
    const int* __restrict__ npts, const float* __restrict__ S,
    const float* __restrict__ gamma, const float* __restrict__ beta,
    float* __restrict__ out) {
  const int c  = threadIdx.x & 63;
  const int wv = threadIdx.x >> 6;
  const int p  = blockIdx.x * 4 + wv;   // 7500*4 == 30000

  const float mean  = S[c] * INV_M;
  const float var   = S[64 + c] * INV_M - mean * mean;
  const float scale = gamma[c] * rsqrtf(var + 0.001f);
  const float shift = beta[c] - mean * scale;

  const int np = npts[p];
  float v = fmaf(scale, out[p * COUT + c], shift);
  if (np < NPT) v = fmaxf(v, shift);   // padded positions contribute relu(shift)
  out[p * COUT + c] = fmaxf(v, 0.f);
}

extern "C" void kernel_launch(void* const* d_in, const int* in_sizes, int n_in,
                              void* d_out, int out_size, void* d_ws, size_t ws_size,
                              hipStream_t stream) {
  const float4* feat  = (const float4*)d_in[0];
  const int*   npts   = (const int*)d_in[1];
  const int*   coords = (const int*)d_in[2];
  const float* W      = (const float*)d_in[3];
  const float* gamma  = (const float*)d_in[4];
  const float* beta   = (const float*)d_in[5];
  float* out = (float*)d_out;

  int nb = 512;
  if (ws_size >= (size_t)(128 + 2048 * 128) * 4) nb = 2048;
  else if (ws_size >= (size_t)(128 + 1024 * 128) * 4) nb = 1024;

  float* S        = (float*)d_ws;   // 128 floats
  float* partials = S + 128;        // nb*128 floats, block-major

  k1_pk<<<nb, 256, 0, stream>>>(feat, npts, coords, W, out, partials, nb);
  k2_reduce<<<1, 1024, 0, stream>>>(partials, nb, S);
  k3_finish<<<P_TOT / 4, 256, 0, stream>>>(npts, S, gamma, beta, out);
}

// Round 8
// 44.533 us; speedup vs baseline: 2.4864x; 2.4864x over previous
//
#include <hip/hip_runtime.h>

#define P_TOT 30000
#define NPT   100
#define COUT  64

typedef __attribute__((ext_vector_type(2))) float f32x2;

static constexpr float VXf   = 0.16f;
static constexpr float VYf   = 0.16f;
static constexpr float XOFFf = 0.08f;            // VX/2 + 0.0
static constexpr float YOFFf = 0.08f - 39.68f;   // VY/2 + y_min
static constexpr float INV_M = 1.0f / 3000000.0f; // 1/(P*N)
static constexpr float NEGI  = -3.0e38f;

__device__ inline float wred(float v) {
#pragma unroll
  for (int d = 1; d < 64; d <<= 1) v += __shfl_xor(v, d);
  return v;
}

// K1: one pass over features, software-pipelined over pillars.
// Per pillar (1 wave, lane = channel): points staged PAIR-TRANSPOSED in LDS:
// pair m -> slot 2m = {x0,x1,y0,y1}, slot 2m+1 = {z0,z1,w0,w1}. Inner loop
// is packed-f32 (v_pk_fma/v_pk_max): 2 points per instruction.
// Bias folded in closed form after the loop:
//   ymax = zmax + b ; Sum(y) = Sz + np*b ; Sum(y^2) = Sq + b*(2*Sz + np*b)
__global__ __launch_bounds__(256) void k1_pk(
    const float4* __restrict__ feat, const int* __restrict__ npts,
    const int* __restrict__ coords, const float* __restrict__ W,
    float* __restrict__ ymax, float* __restrict__ partials, int nb) {
  const int lane = threadIdx.x & 63;
  const int wv   = threadIdx.x >> 6;
  const int wave_id = blockIdx.x * 4 + wv;
  const int nwaves  = nb * 4;

  // per-channel weights, affine-folded: ce = (w0+w4+w7, w1+w5+w8, w2+w6, w3)
  float wr[9];
#pragma unroll
  for (int i = 0; i < 9; i++) wr[i] = W[lane * 9 + i];
  const float ce0 = wr[0] + wr[4] + wr[7];
  const float ce1 = wr[1] + wr[5] + wr[8];
  const float ce2 = wr[2] + wr[6];
  const float ce3 = wr[3];
  const f32x2 cex2 = {ce0, ce0};
  const f32x2 cey2 = {ce1, ce1};
  const f32x2 cez2 = {ce2, ce2};
  const f32x2 cew2 = {ce3, ce3};

  float sum = 0.f, sumsq = 0.f;
  __shared__ float4 pts[4][NPT];   // pair-transposed staging, per wave

  const bool even = (lane & 1) == 0;

  // prologue: load pillar wave_id
  int p = wave_id;
  float4 a0 = make_float4(0.f, 0.f, 0.f, 0.f), a1 = a0;
  int np = 1, cx = 0, cy = 0;
  if (p < P_TOT) {
    const float4* fp = feat + (size_t)p * NPT;
    a0 = fp[lane];
    if (lane < 36) a1 = fp[lane + 64];
    np = npts[p];
    cx = coords[p * 4 + 3];
    cy = coords[p * 4 + 2];
  }

  while (p < P_TOT) {
    // prefetch next pillar (hides HBM latency under this pillar's compute)
    const int pn = p + nwaves;
    float4 b0 = make_float4(0.f, 0.f, 0.f, 0.f), b1 = b0;
    int npn = 1, cxn = 0, cyn = 0;
    if (pn < P_TOT) {
      const float4* fpn = feat + (size_t)pn * NPT;
      b0 = fpn[lane];
      if (lane < 36) b1 = fpn[lane + 64];
      npn = npts[pn];
      cxn = coords[pn * 4 + 3];
      cyn = coords[pn * 4 + 2];
    }

    // pair-transpose exchange: even lane sends (z,w), odd sends (x,y)
    {
      const float s0 = even ? a0.z : a0.x;
      const float s1 = even ? a0.w : a0.y;
      const float r0 = __shfl_xor(s0, 1);
      const float r1 = __shfl_xor(s1, 1);
      // even lane -> slot 2m   = {x0, x1, y0, y1}
      // odd  lane -> slot 2m+1 = {z0, z1, w0, w1}
      pts[wv][lane] = even ? make_float4(a0.x, r0, a0.y, r1)
                           : make_float4(r0, a0.z, r1, a0.w);
    }
    if (lane < 36) {
      const float s0 = even ? a1.z : a1.x;
      const float s1 = even ? a1.w : a1.y;
      const float r0 = __shfl_xor(s0, 1);
      const float r1 = __shfl_xor(s1, 1);
      pts[wv][lane + 64] = even ? make_float4(a1.x, r0, a1.y, r1)
                                : make_float4(r0, a1.z, r1, a1.w);
    }
    asm volatile("s_waitcnt lgkmcnt(0)" ::: "memory");

    const float4* base = pts[wv];
    f32x2 zmA = {NEGI, NEGI}, zmB = {NEGI, NEGI};
    f32x2 zsA = {0.f, 0.f}, zsB = {0.f, 0.f};
    f32x2 zqA = {0.f, 0.f}, zqB = {0.f, 0.f};

    const int Pp = np >> 1;   // full pairs
    int m = 0;
    for (; m + 2 <= Pp; m += 2) {
      const float4 u0 = base[2 * m];
      const float4 u1 = base[2 * m + 1];
      const float4 v0 = base[2 * m + 2];
      const float4 v1 = base[2 * m + 3];
      f32x2 z1 = f32x2{u0.x, u0.y} * cex2;
      f32x2 z2 = f32x2{v0.x, v0.y} * cex2;
      z1 += f32x2{u0.z, u0.w} * cey2;
      z2 += f32x2{v0.z, v0.w} * cey2;
      z1 += f32x2{u1.x, u1.y} * cez2;
      z2 += f32x2{v1.x, v1.y} * cez2;
      z1 += f32x2{u1.z, u1.w} * cew2;
      z2 += f32x2{v1.z, v1.w} * cew2;
      zmA = __builtin_elementwise_max(zmA, z1);
      zmB = __builtin_elementwise_max(zmB, z2);
      zsA += z1;
      zsB += z2;
      zqA += z1 * z1;
      zqB += z2 * z2;
    }
    if (m < Pp) {
      const float4 u0 = base[2 * m];
      const float4 u1 = base[2 * m + 1];
      f32x2 z1 = f32x2{u0.x, u0.y} * cex2;
      z1 += f32x2{u0.z, u0.w} * cey2;
      z1 += f32x2{u1.x, u1.y} * cez2;
      z1 += f32x2{u1.z, u1.w} * cew2;
      zmA = __builtin_elementwise_max(zmA, z1);
      zsA += z1;
      zqA += z1 * z1;
    }
    if (np & 1) {
      // last point np-1 (even parity) sits in pair Pp, parity-0 fields
      const float4 u0 = base[2 * Pp];
      const float4 u1 = base[2 * Pp + 1];
      float zx = u0.x * ce0;
      zx = fmaf(u0.z, ce1, zx);
      zx = fmaf(u1.x, ce2, zx);
      zx = fmaf(u1.z, ce3, zx);
      zmA.x = fmaxf(zmA.x, zx);
      zsA.x += zx;
      zqA.x = fmaf(zx, zx, zqA.x);
    }

    // cross-lane xyz sums AFTER the z-loop (reference: sum ALL 100 rows / np)
    const float sax = wred(a0.x + a1.x);
    const float say = wred(a0.y + a1.y);
    const float saz = wred(a0.z + a1.z);
    const float inv = 1.f / (float)np;
    const float cxc = (float)cx * VXf + XOFFf;
    const float cyc = (float)cy * VYf + YOFFf;
    float b = wr[4] * (sax * inv);
    b = fmaf(wr[5], say * inv, b);
    b = fmaf(wr[6], saz * inv, b);
    b = fmaf(wr[7], cxc, b);
    b = fmaf(wr[8], cyc, b);
    b = -b;

    const float zm = fmaxf(fmaxf(zmA.x, zmA.y), fmaxf(zmB.x, zmB.y));
    const float zs = (zsA.x + zsA.y) + (zsB.x + zsB.y);
    const float zq = (zqA.x + zqA.y) + (zqB.x + zqB.y);
    const float npf = (float)np;
    ymax[p * COUT + lane] = zm + b;
    sum   += zs + npf * b;
    sumsq += zq + b * fmaf(npf, b, 2.f * zs);

    p = pn;
    a0 = b0; a1 = b1; np = npn; cx = cxn; cy = cyn;
  }

  __syncthreads();
  __shared__ float rs[4][64], rq[4][64];
  rs[wv][lane] = sum;
  rq[wv][lane] = sumsq;
  __syncthreads();
  const int t = threadIdx.x;
  if (t < 128) {
    const int c = t & 63;
    float v;
    if (t < 64) v = rs[0][c] + rs[1][c] + rs[2][c] + rs[3][c];
    else        v = rq[0][c] + rq[1][c] + rq[2][c] + rq[3][c];
    partials[(size_t)blockIdx.x * 128 + t] = v;   // coalesced, block-major
  }
}

// K2: 128 blocks (one per moment), 256 threads each -> TLP hides latency
__global__ __launch_bounds__(256) void k2_reduce(
    const float* __restrict__ partials, int nb, float* __restrict__ S) {
  const int m = blockIdx.x;
  float s = 0.f;
  for (int b = threadIdx.x; b < nb; b += 256) s += partials[(size_t)b * 128 + m];
  s = wred(s);
  __shared__ float t4[4];
  if ((threadIdx.x & 63) == 0) t4[threadIdx.x >> 6] = s;
  __syncthreads();
  if (threadIdx.x == 0) S[m] = t4[0] + t4[1] + t4[2] + t4[3];
}

// K3: finish in place on d_out. Each thread derives its channel's scale/shift
// from S (gamma==1 => scale>0, so max commutes with the BN affine).
__global__ __launch_bounds__(256) void k3_finish(
    const int* __restrict__ npts, const float* __restrict__ S,
    const float* __restrict__ gamma, const float* __restrict__ beta,
    float* __restrict__ out) {
  const int c  = threadIdx.x & 63;
  const int wv = threadIdx.x >> 6;
  const int p  = blockIdx.x * 4 + wv;   // 7500*4 == 30000

  const float mean  = S[c] * INV_M;
  const float var   = S[64 + c] * INV_M - mean * mean;
  const float scale = gamma[c] * rsqrtf(var + 0.001f);
  const float shift = beta[c] - mean * scale;

  const int np = npts[p];
  float v = fmaf(scale, out[p * COUT + c], shift);
  if (np < NPT) v = fmaxf(v, shift);   // padded positions contribute relu(shift)
  out[p * COUT + c] = fmaxf(v, 0.f);
}

extern "C" void kernel_launch(void* const* d_in, const int* in_sizes, int n_in,
                              void* d_out, int out_size, void* d_ws, size_t ws_size,
                              hipStream_t stream) {
  const float4* feat  = (const float4*)d_in[0];
  const int*   npts   = (const int*)d_in[1];
  const int*   coords = (const int*)d_in[2];
  const float* W      = (const float*)d_in[3];
  const float* gamma  = (const float*)d_in[4];
  const float* beta   = (const float*)d_in[5];
  float* out = (float*)d_out;

  int nb = 512;
  if (ws_size >= (size_t)(128 + 2048 * 128) * 4) nb = 2048;
  else if (ws_size >= (size_t)(128 + 1024 * 128) * 4) nb = 1024;

  float* S        = (float*)d_ws;   // 128 floats
  float* partials = S + 128;        // nb*128 floats, block-major

  k1_pk<<<nb, 256, 0, stream>>>(feat, npts, coords, W, out, partials, nb);
  k2_reduce<<<128, 256, 0, stream>>>(partials, nb, S);
  k3_finish<<<P_TOT / 4, 256, 0, stream>>>(npts, S, gamma, beta, out);
}